// Round 1
// baseline (605.024 us; speedup 1.0000x reference)
//
#include <hip/hip_runtime.h>
#include <stdint.h>

// LinearAttention on MI355X.
// Math: final[b,o,n] = sum_c M_b[o,c] x[b,c,n] + b_out[o]
//   M_b = W_out * blockdiag_h(ctx_h^T) * W_q
//   ctx[hd][e] = (1/Z[hd]) sum_c A[hd][c] Wv[32h+e][c]
//   A[hd][c]   = sum_n exp(k[hd,n]) x[c,n],  Z[hd] = sum_n exp(k[hd,n])
//   k[hd,n]    = sum_c Wk[hd][c] x[c,n]
// (no max-subtraction: k ~ N(0,0.4^2), exp bounded ~[0.05,15], fp32-safe)

#define N_POS 81920   // 80*1024
#define NB    8
#define NT    128     // positions per tile in kernA
#define TILES 640     // per batch: 81920/128

__device__ __forceinline__ float bflo(uint32_t u){ return __uint_as_float(u << 16); }
__device__ __forceinline__ float bfhi(uint32_t u){ return __uint_as_float(u & 0xffff0000u); }
__device__ __forceinline__ uint32_t packbf(float lo, float hi){
  uint32_t a = __float_as_uint(lo), b = __float_as_uint(hi);
  a = (a + 0x8000u) >> 16;          // ~round-to-nearest bf16
  b = (b + 0x8000u) & 0xffff0000u;
  return a | b;
}

// ---------------------------------------------------------------------------
// kernA: per (batch, n-chunk): accumulate partial A[128][64], Z[128].
// LDS 64KB: xs = x-tile bf16 [64 c][128 pos] (16KB, row-XOR swizzled 16B chunks)
//           es = E-tile bf16 [128 hd][128 pos] (32KB, swizzled)
//           wk = Wk bf16 [64 c][128 hd] (16KB)
// Phase1: thread (hx=t&15, q=t>>4) computes k/e for hd 8hx..+7, pos 8q..+7.
// Phase2: same thread accumulates A rows 8hx..+7, cols 4q..+3 over tile.
// ---------------------------------------------------------------------------
__global__ __launch_bounds__(256, 2) void kernA(
    const float* __restrict__ x, const float* __restrict__ w,
    float* __restrict__ pA, float* __restrict__ pZ, int nch, int tpc)
{
  __shared__ __align__(16) uint32_t xs[64 * 64];    // 64 rows * 16 chunks(4 u32)
  __shared__ __align__(16) uint32_t es[128 * 64];   // 128 rows * 16 chunks
  __shared__ __align__(16) uint16_t wk[64 * 128];   // [c][hd]

  const int t  = threadIdx.x;
  const int b  = blockIdx.x / nch;
  const int ch = blockIdx.x % nch;
  const int hx = t & 15;
  const int q  = t >> 4;          // pos-group in phase1, c-group in phase2

  // stage Wk (rows 128..255 of w_qkv) as bf16 [c][hd]
  for (int i = t; i < 8192; i += 256){
    int hd = i & 127, c = i >> 7;
    float v = w[(128 + hd) * 64 + c];
    wk[c * 128 + hd] = (uint16_t)((__float_as_uint(v) + 0x8000u) >> 16);
  }

  float acc[8][4];
  #pragma unroll
  for (int j = 0; j < 8; ++j)
    #pragma unroll
    for (int jc = 0; jc < 4; ++jc) acc[j][jc] = 0.f;
  float z = 0.f;

  const float* xb = x + (size_t)b * 64 * N_POS;
  __syncthreads();

  for (int tile = 0; tile < tpc; ++tile){
    const int n0 = (ch * tpc + tile) * NT;
    __syncthreads();   // previous phase2/z done with xs/es

    // ---- stage x-tile -> bf16 LDS (row-XOR swizzle on 16B chunks) ----
    {
      const int j = t & 15, r4 = t >> 4;
      #pragma unroll
      for (int k = 0; k < 4; ++k){
        const int r = r4 + 16 * k;
        const float* g = xb + (size_t)r * N_POS + n0 + j * 8;
        float4 g0 = *(const float4*)g;
        float4 g1 = *(const float4*)(g + 4);
        uint4 v;
        v.x = packbf(g0.x, g0.y); v.y = packbf(g0.z, g0.w);
        v.z = packbf(g1.x, g1.y); v.w = packbf(g1.z, g1.w);
        *(uint4*)&xs[r * 64 + (j ^ ((r >> 2) & 7)) * 4] = v;
      }
    }
    __syncthreads();

    // ---- phase1: k = Wk * x-tile; e = exp(k) -> es ----
    {
      float ka[8][8];
      #pragma unroll
      for (int j = 0; j < 8; ++j)
        #pragma unroll
        for (int p = 0; p < 8; ++p) ka[j][p] = 0.f;

      #pragma unroll 4
      for (int c = 0; c < 64; ++c){
        uint4 wv = *(const uint4*)&wk[c * 128 + hx * 8];
        uint4 xv = *(const uint4*)&xs[c * 64 + (q ^ ((c >> 2) & 7)) * 4];
        float wf[8] = { bflo(wv.x), bfhi(wv.x), bflo(wv.y), bfhi(wv.y),
                        bflo(wv.z), bfhi(wv.z), bflo(wv.w), bfhi(wv.w) };
        float xp[8] = { bflo(xv.x), bfhi(xv.x), bflo(xv.y), bfhi(xv.y),
                        bflo(xv.z), bfhi(xv.z), bflo(xv.w), bfhi(xv.w) };
        #pragma unroll
        for (int j = 0; j < 8; ++j)
          #pragma unroll
          for (int p = 0; p < 8; ++p)
            ka[j][p] = fmaf(wf[j], xp[p], ka[j][p]);
      }
      #pragma unroll
      for (int j = 0; j < 8; ++j){
        const int row = 8 * hx + j;
        float e0 = __expf(ka[j][0]), e1 = __expf(ka[j][1]);
        float e2 = __expf(ka[j][2]), e3 = __expf(ka[j][3]);
        float e4 = __expf(ka[j][4]), e5 = __expf(ka[j][5]);
        float e6 = __expf(ka[j][6]), e7 = __expf(ka[j][7]);
        uint4 ev;
        ev.x = packbf(e0, e1); ev.y = packbf(e2, e3);
        ev.z = packbf(e4, e5); ev.w = packbf(e6, e7);
        *(uint4*)&es[row * 64 + (q ^ (hx & 7)) * 4] = ev;
      }
    }
    __syncthreads();

    // ---- phase2: A[8hx+j][4q+jc] += sum_pos e * x ----
    for (int s = 0; s < 16; ++s){
      float xv[4][8];
      #pragma unroll
      for (int jc = 0; jc < 4; ++jc){
        uint4 v = *(const uint4*)&xs[(4 * q + jc) * 64 + (s ^ (q & 7)) * 4];
        xv[jc][0] = bflo(v.x); xv[jc][1] = bfhi(v.x);
        xv[jc][2] = bflo(v.y); xv[jc][3] = bfhi(v.y);
        xv[jc][4] = bflo(v.z); xv[jc][5] = bfhi(v.z);
        xv[jc][6] = bflo(v.w); xv[jc][7] = bfhi(v.w);
      }
      #pragma unroll
      for (int j = 0; j < 8; ++j){
        uint4 ev = *(const uint4*)&es[(8 * hx + j) * 64 + (s ^ (hx & 7)) * 4];
        float e[8] = { bflo(ev.x), bfhi(ev.x), bflo(ev.y), bfhi(ev.y),
                       bflo(ev.z), bfhi(ev.z), bflo(ev.w), bfhi(ev.w) };
        #pragma unroll
        for (int p = 0; p < 8; ++p)
          #pragma unroll
          for (int jc = 0; jc < 4; ++jc)
            acc[j][jc] = fmaf(e[p], xv[jc][p], acc[j][jc]);
      }
    }
    // ---- z-pass (waves 0,1): Z[hd] partials ----
    if (t < 128){
      #pragma unroll 2
      for (int s = 0; s < 16; ++s){
        uint4 ev = *(const uint4*)&es[t * 64 + (s ^ ((t >> 3) & 7)) * 4];
        z += bflo(ev.x) + bfhi(ev.x) + bflo(ev.y) + bfhi(ev.y)
           + bflo(ev.z) + bfhi(ev.z) + bflo(ev.w) + bfhi(ev.w);
      }
    }
  }

  float* pa = pA + (size_t)blockIdx.x * 8192;
  #pragma unroll
  for (int j = 0; j < 8; ++j){
    float4 v = make_float4(acc[j][0], acc[j][1], acc[j][2], acc[j][3]);
    *(float4*)&pa[(8 * hx + j) * 64 + 4 * q] = v;
  }
  if (t < 128) pZ[(size_t)blockIdx.x * 128 + t] = z;
}

// ---------------------------------------------------------------------------
// kernR: per batch: reduce partials -> A,Z; ctx[hd][e] = (A[hd]·Wv[e]) / Z[hd]
// ---------------------------------------------------------------------------
__global__ __launch_bounds__(256) void kernR(
    const float* __restrict__ pA, const float* __restrict__ pZ,
    const float* __restrict__ w, float* __restrict__ ctx, int nch)
{
  __shared__ float A[128 * 65];
  __shared__ float Z[128];
  const int b = blockIdx.x, t = threadIdx.x;

  float s[32];
  #pragma unroll
  for (int k = 0; k < 32; ++k) s[k] = 0.f;
  for (int ch = 0; ch < nch; ++ch){
    const float* base = pA + (size_t)(b * nch + ch) * 8192;
    #pragma unroll
    for (int k = 0; k < 32; ++k) s[k] += base[t + 256 * k];
  }
  #pragma unroll
  for (int k = 0; k < 32; ++k){
    int i = t + 256 * k;
    A[(i >> 6) * 65 + (i & 63)] = s[k];
  }
  if (t < 128){
    float zz = 0.f;
    for (int ch = 0; ch < nch; ++ch) zz += pZ[(size_t)(b * nch + ch) * 128 + t];
    Z[t] = zz;
  }
  __syncthreads();

  const int hd = t & 127, h = hd >> 5, e0 = (t >> 7) * 16;
  const float rz = 1.0f / Z[hd];
  for (int je = 0; je < 16; ++je){
    int e = e0 + je;
    const float* wv = w + (size_t)(256 + 32 * h + e) * 64;   // Wv row
    float a = 0.f;
    #pragma unroll
    for (int c = 0; c < 64; ++c) a = fmaf(A[hd * 65 + c], wv[c], a);
    ctx[((size_t)b * 128 + hd) * 32 + e] = a * rz;
  }
}

// ---------------------------------------------------------------------------
// kernM: per batch: T[o][hd] = sum_e w_out[o][32h+e] ctx[hd][e];
//        M[o][c] = sum_hd T[o][hd] Wq[hd][c]
// ---------------------------------------------------------------------------
__global__ __launch_bounds__(256) void kernM(
    const float* __restrict__ ctx, const float* __restrict__ w_qkv,
    const float* __restrict__ w_out, float* __restrict__ M)
{
  __shared__ float cs[128 * 33];
  __shared__ float T[64 * 129];
  const int b = blockIdx.x, t = threadIdx.x;

  #pragma unroll
  for (int k = 0; k < 16; ++k){
    int i = t + 256 * k;
    cs[(i >> 5) * 33 + (i & 31)] = ctx[(size_t)b * 4096 + i];
  }
  __syncthreads();

  const int o = t & 63, g = t >> 6;
  for (int jh = 0; jh < 32; ++jh){
    int hd = 32 * g + jh, h = g;
    const float* wo = w_out + (size_t)o * 128 + 32 * h;
    float a = 0.f;
    #pragma unroll
    for (int e = 0; e < 32; ++e) a = fmaf(wo[e], cs[hd * 33 + e], a);
    T[o * 129 + hd] = a;
  }
  __syncthreads();

  const int c0 = 16 * g;
  float m[16];
  #pragma unroll
  for (int j = 0; j < 16; ++j) m[j] = 0.f;
  for (int hd = 0; hd < 128; ++hd){
    float tv = T[o * 129 + hd];
    const float* wq = w_qkv + (size_t)hd * 64 + c0;
    #pragma unroll
    for (int j = 0; j < 16; ++j) m[j] = fmaf(tv, wq[j], m[j]);
  }
  #pragma unroll
  for (int j = 0; j < 16; ++j) M[(size_t)b * 4096 + o * 64 + c0 + j] = m[j];
}

// ---------------------------------------------------------------------------
// kernO: out[b,o,n] = sum_c M_b[o][c] x[b,c,n] + b_out[o]
// Thread = one position; x column in 64 VGPRs; M via uniform (scalar) loads.
// ---------------------------------------------------------------------------
__global__ __launch_bounds__(256) void kernO(
    const float* __restrict__ x, const float* __restrict__ M,
    const float* __restrict__ b_out, float* __restrict__ out)
{
  const int blk = blockIdx.x;
  const int b   = blk / 320;
  const int pos = (blk % 320) * 256 + threadIdx.x;
  const float* xb = x + (size_t)b * 64 * N_POS + pos;

  float xr[64];
  #pragma unroll
  for (int c = 0; c < 64; ++c) xr[c] = xb[(size_t)c * N_POS];

  const float* Mb = M + (size_t)b * 4096;
  float* ob = out + (size_t)b * 64 * N_POS + pos;

  for (int o = 0; o < 64; ++o){
    const float* mr = Mb + o * 64;
    float a0 = b_out[o], a1 = 0.f, a2 = 0.f, a3 = 0.f;
    #pragma unroll
    for (int c4 = 0; c4 < 16; ++c4){
      a0 = fmaf(mr[4 * c4 + 0], xr[4 * c4 + 0], a0);
      a1 = fmaf(mr[4 * c4 + 1], xr[4 * c4 + 1], a1);
      a2 = fmaf(mr[4 * c4 + 2], xr[4 * c4 + 2], a2);
      a3 = fmaf(mr[4 * c4 + 3], xr[4 * c4 + 3], a3);
    }
    ob[(size_t)o * N_POS] = (a0 + a1) + (a2 + a3);
  }
}

// ---------------------------------------------------------------------------
extern "C" void kernel_launch(void* const* d_in, const int* in_sizes, int n_in,
                              void* d_out, int out_size, void* d_ws, size_t ws_size,
                              hipStream_t stream)
{
  const float* x     = (const float*)d_in[0];
  const float* w_qkv = (const float*)d_in[1];
  const float* w_out = (const float*)d_in[2];
  const float* b_out = (const float*)d_in[3];
  float* out = (float*)d_out;
  float* ws  = (float*)d_ws;

  // split-K chunks per batch (must divide 640); shrink if ws is small
  static const int cand[] = {64, 40, 32, 20, 16, 10, 8, 5, 4, 2, 1};
  int nch = 1;
  for (int i = 0; i < 11; ++i){
    size_t need = ((size_t)8 * cand[i] * (8192 + 128) + 2 * 8 * 4096) * 4;
    if (need <= ws_size){ nch = cand[i]; break; }
  }
  const int tpc = TILES / nch;

  float* pA  = ws;
  float* pZ  = pA + (size_t)8 * nch * 8192;
  float* ctx = pZ + (size_t)8 * nch * 128;
  float* M   = ctx + (size_t)8 * 4096;

  kernA<<<8 * nch, 256, 0, stream>>>(x, w_qkv, pA, pZ, nch, tpc);
  kernR<<<8,       256, 0, stream>>>(pA, pZ, w_qkv, ctx, nch);
  kernM<<<8,       256, 0, stream>>>(ctx, w_qkv, w_out, M);
  kernO<<<2560,    256, 0, stream>>>(x, M, b_out, out);
}

// Round 3
// 337.028 us; speedup vs baseline: 1.7952x; 1.7952x over previous
//
#include <hip/hip_runtime.h>
#include <stdint.h>

// LinearAttention, MFMA kernA (R2 fix: K-chunk offsets 16*kk -> 32*kk).
// Math: final[b,o,n] = sum_c M_b[o,c] x[b,c,n] + b_out[o]
//   M_b = W_out * blockdiag_h(ctx_h^T) * W_q
//   ctx[hd][e] = (1/Z[hd]) sum_c A[hd][c] Wv[32h+e][c]
//   A[hd][c]   = sum_n exp(k[hd,n]) x[c,n],  Z[hd] = sum_n exp(k[hd,n])
//   k[hd,n]    = sum_c Wk[hd][c] x[c,n]   (k ~ N(0,0.4^2): exp fp32-safe)

#define N_POS 81920   // 80*1024
#define NT    64      // positions per kernA tile
#define TILES 1280    // tiles per batch

typedef short bf16x8 __attribute__((ext_vector_type(8)));
typedef float f32x4  __attribute__((ext_vector_type(4)));

__device__ __forceinline__ uint32_t packbf(float lo, float hi){
  uint32_t a = __float_as_uint(lo), b = __float_as_uint(hi);
  a = (a + 0x8000u) >> 16;
  b = (b + 0x8000u) & 0xffff0000u;
  return a | b;
}
__device__ __forceinline__ short bf16of(float v){
  return (short)((__float_as_uint(v) + 0x8000u) >> 16);
}

// ---------------------------------------------------------------------------
// kernA: per (batch, chunk): partial A[128][64], Z[128] via MFMA.
// LDS (pitch 72 bf16 = 144B rows):
//   xs_cp[c][pos]  : phase2 B-operand (k=pos contiguous)
//   xs_pc[pos][c]  : phase1 A-operand (k=c contiguous)
//   es   [hd][pos] : E=exp(k), phase2 A-operand
// MFMA 16x16x32 fragment layouts (verified m89):
//   A: row=lane&15,  k=(lane>>4)*8+j   -> 32-wide K-chunks
//   B: col=lane&15,  k=(lane>>4)*8+j
//   D: col=lane&15,  row=(lane>>4)*4+r
// ---------------------------------------------------------------------------
__global__ __launch_bounds__(256, 2) void kernA(
    const float* __restrict__ x, const float* __restrict__ w,
    float* __restrict__ pA, float* __restrict__ pZ, int nch, int tpc)
{
  __shared__ __align__(16) uint16_t xs_cp[64 * 72];
  __shared__ __align__(16) uint16_t xs_pc[64 * 72];
  __shared__ __align__(16) uint16_t es[128 * 72];

  const int t  = threadIdx.x;
  const int wv = t >> 6;     // wave 0..3
  const int l  = t & 63;
  const int lm = l & 15;     // fragment row/col
  const int lg = l >> 4;     // fragment k-group

  const int b  = blockIdx.x / nch;
  const int ch = blockIdx.x % nch;
  const float* xb = x + (size_t)b * 64 * N_POS;

  // Wk (w_qkv rows 128..255) as phase1 B-fragments, kept in registers.
  // wkf[ht][kk]: lane holds Wk[16ht+lm][32kk+8lg+j], j=0..7
  bf16x8 wkf[8][2];
  #pragma unroll
  for (int ht = 0; ht < 8; ++ht)
    #pragma unroll
    for (int kk = 0; kk < 2; ++kk){
      const float* wp = w + (size_t)(128 + 16*ht + lm) * 64 + 32*kk + 8*lg;
      float4 w0 = *(const float4*)wp;
      float4 w1 = *(const float4*)(wp + 4);
      bf16x8 f;
      f[0]=bf16of(w0.x); f[1]=bf16of(w0.y); f[2]=bf16of(w0.z); f[3]=bf16of(w0.w);
      f[4]=bf16of(w1.x); f[5]=bf16of(w1.y); f[6]=bf16of(w1.z); f[7]=bf16of(w1.w);
      wkf[ht][kk] = f;
    }

  bf16x8 ones;
  #pragma unroll
  for (int j = 0; j < 8; ++j) ones[j] = (short)0x3F80;   // bf16 1.0

  f32x4 acc[2][4], zac[2];
  #pragma unroll
  for (int m = 0; m < 2; ++m){
    zac[m] = (f32x4){0.f,0.f,0.f,0.f};
    #pragma unroll
    for (int n = 0; n < 4; ++n) acc[m][n] = (f32x4){0.f,0.f,0.f,0.f};
  }

  for (int tile = 0; tile < tpc; ++tile){
    const int n0 = (ch * tpc + tile) * NT;
    __syncthreads();   // prior phase2 done with xs_cp/es

    // stage xs_cp[c][pos]: thread: row rr, 16-pos slice pc (coalesced 64B/row)
    {
      const int rr = t >> 2, pc = t & 3;
      const float* g = xb + (size_t)rr * N_POS + n0 + 16*pc;
      float4 a0 = *(const float4*)g;
      float4 a1 = *(const float4*)(g + 4);
      float4 a2 = *(const float4*)(g + 8);
      float4 a3 = *(const float4*)(g + 12);
      uint4 v0, v1;
      v0.x = packbf(a0.x,a0.y); v0.y = packbf(a0.z,a0.w);
      v0.z = packbf(a1.x,a1.y); v0.w = packbf(a1.z,a1.w);
      v1.x = packbf(a2.x,a2.y); v1.y = packbf(a2.z,a2.w);
      v1.z = packbf(a3.x,a3.y); v1.w = packbf(a3.z,a3.w);
      *(uint4*)&xs_cp[rr*72 + 16*pc]     = v0;
      *(uint4*)&xs_cp[rr*72 + 16*pc + 8] = v1;
    }
    // stage xs_pc[pos][c]: thread = one pos, 16 c (each load 256B-coalesced)
    {
      const int pp = t & 63, c0 = (t >> 6) * 16;
      float v[16];
      #pragma unroll
      for (int i = 0; i < 16; ++i)
        v[i] = xb[(size_t)(c0 + i) * N_POS + n0 + pp];
      uint4 u0, u1;
      u0.x = packbf(v[0],v[1]);   u0.y = packbf(v[2],v[3]);
      u0.z = packbf(v[4],v[5]);   u0.w = packbf(v[6],v[7]);
      u1.x = packbf(v[8],v[9]);   u1.y = packbf(v[10],v[11]);
      u1.z = packbf(v[12],v[13]); u1.w = packbf(v[14],v[15]);
      *(uint4*)&xs_pc[pp*72 + c0]     = u0;
      *(uint4*)&xs_pc[pp*72 + c0 + 8] = u1;
    }
    __syncthreads();

    // phase1: wave wv owns pos-tile wv. S[pos][hd], then E=exp -> es[hd][pos]
    {
      bf16x8 af0 = *(const bf16x8*)&xs_pc[(16*wv + lm)*72 + 8*lg];        // c 0..31
      bf16x8 af1 = *(const bf16x8*)&xs_pc[(16*wv + lm)*72 + 32 + 8*lg];   // c 32..63
      #pragma unroll
      for (int ht = 0; ht < 8; ++ht){
        f32x4 s = (f32x4){0.f,0.f,0.f,0.f};
        s = __builtin_amdgcn_mfma_f32_16x16x32_bf16(af0, wkf[ht][0], s, 0,0,0);
        s = __builtin_amdgcn_mfma_f32_16x16x32_bf16(af1, wkf[ht][1], s, 0,0,0);
        // lane holds pos = 16wv+4lg+r (r=0..3), hd = 16ht+lm
        float e0 = __expf(s[0]), e1 = __expf(s[1]);
        float e2 = __expf(s[2]), e3 = __expf(s[3]);
        uint2 pk; pk.x = packbf(e0,e1); pk.y = packbf(e2,e3);
        *(uint2*)&es[(16*ht + lm)*72 + 16*wv + 4*lg] = pk;
      }
    }
    __syncthreads();

    // phase2: wave wv owns hd-tiles {2wv, 2wv+1} x all 4 c-tiles
    #pragma unroll
    for (int kk = 0; kk < 2; ++kk){
      bf16x8 ea[2], xbf[4];
      #pragma unroll
      for (int m = 0; m < 2; ++m)
        ea[m] = *(const bf16x8*)&es[(16*(2*wv+m) + lm)*72 + 32*kk + 8*lg];
      #pragma unroll
      for (int n = 0; n < 4; ++n)
        xbf[n] = *(const bf16x8*)&xs_cp[(16*n + lm)*72 + 32*kk + 8*lg];
      #pragma unroll
      for (int m = 0; m < 2; ++m){
        #pragma unroll
        for (int n = 0; n < 4; ++n)
          acc[m][n] = __builtin_amdgcn_mfma_f32_16x16x32_bf16(ea[m], xbf[n], acc[m][n], 0,0,0);
        zac[m] = __builtin_amdgcn_mfma_f32_16x16x32_bf16(ea[m], ones, zac[m], 0,0,0);
      }
    }
  }

  // epilogue: acc D-layout: row hd = 16(2wv+m)+4lg+r, col c = 16n+lm
  float* pa = pA + (size_t)blockIdx.x * 8192;
  #pragma unroll
  for (int m = 0; m < 2; ++m){
    const int hd0 = 16*(2*wv + m) + 4*lg;
    #pragma unroll
    for (int n = 0; n < 4; ++n)
      #pragma unroll
      for (int r = 0; r < 4; ++r)
        pa[(size_t)(hd0 + r)*64 + 16*n + lm] = acc[m][n][r];
    if (lm == 0){
      #pragma unroll
      for (int r = 0; r < 4; ++r)
        pZ[(size_t)blockIdx.x * 128 + hd0 + r] = zac[m][r];
    }
  }
}

// ---------------------------------------------------------------------------
// kernR1: parallel reduce of partials. grid 64 = 8 batches x 8 slices.
// ---------------------------------------------------------------------------
__global__ __launch_bounds__(256) void kernR1(
    const float* __restrict__ pA, const float* __restrict__ pZ,
    float* __restrict__ Ar, float* __restrict__ Zr, int nch)
{
  const int b = blockIdx.x >> 3, s = blockIdx.x & 7;
  const int off = s * 1024 + threadIdx.x * 4;
  float4 a = make_float4(0.f, 0.f, 0.f, 0.f);
  for (int ch = 0; ch < nch; ++ch){
    float4 v = *(const float4*)&pA[(size_t)(b * nch + ch) * 8192 + off];
    a.x += v.x; a.y += v.y; a.z += v.z; a.w += v.w;
  }
  *(float4*)&Ar[(size_t)b * 8192 + off] = a;
  if (s == 0 && threadIdx.x < 128){
    float z = 0.f;
    for (int ch = 0; ch < nch; ++ch) z += pZ[(size_t)(b * nch + ch) * 128 + threadIdx.x];
    Zr[b * 128 + threadIdx.x] = z;
  }
}

// ---------------------------------------------------------------------------
// kernR2: per batch: ctx[hd][e] = (A[hd]·Wv[e]) / Z[hd]
// ---------------------------------------------------------------------------
__global__ __launch_bounds__(256) void kernR2(
    const float* __restrict__ Ar, const float* __restrict__ Zr,
    const float* __restrict__ w, float* __restrict__ ctx)
{
  __shared__ float A[128 * 65];
  __shared__ float Z[128];
  const int b = blockIdx.x, t = threadIdx.x;

  #pragma unroll
  for (int k = 0; k < 32; ++k){
    int i = t + 256 * k;
    A[(i >> 6) * 65 + (i & 63)] = Ar[(size_t)b * 8192 + i];
  }
  if (t < 128) Z[t] = Zr[b * 128 + t];
  __syncthreads();

  const int hd = t & 127, h = hd >> 5, e0 = (t >> 7) * 16;
  const float rz = 1.0f / Z[hd];
  for (int je = 0; je < 16; ++je){
    int e = e0 + je;
    const float* wv = w + (size_t)(256 + 32 * h + e) * 64;   // Wv row
    float a = 0.f;
    #pragma unroll
    for (int c = 0; c < 64; ++c) a = fmaf(A[hd * 65 + c], wv[c], a);
    ctx[((size_t)b * 128 + hd) * 32 + e] = a * rz;
  }
}

// ---------------------------------------------------------------------------
// kernM: per batch: T[o][hd] = sum_e w_out[o][32h+e] ctx[hd][e];
//        M[o][c] = sum_hd T[o][hd] Wq[hd][c]
// ---------------------------------------------------------------------------
__global__ __launch_bounds__(256) void kernM(
    const float* __restrict__ ctx, const float* __restrict__ w_qkv,
    const float* __restrict__ w_out, float* __restrict__ M)
{
  __shared__ float cs[128 * 33];
  __shared__ float T[64 * 129];
  const int b = blockIdx.x, t = threadIdx.x;

  #pragma unroll
  for (int k = 0; k < 16; ++k){
    int i = t + 256 * k;
    cs[(i >> 5) * 33 + (i & 31)] = ctx[(size_t)b * 4096 + i];
  }
  __syncthreads();

  const int o = t & 63, g = t >> 6;
  for (int jh = 0; jh < 32; ++jh){
    int hd = 32 * g + jh, h = g;
    const float* wo = w_out + (size_t)o * 128 + 32 * h;
    float a = 0.f;
    #pragma unroll
    for (int e = 0; e < 32; ++e) a = fmaf(wo[e], cs[hd * 33 + e], a);
    T[o * 129 + hd] = a;
  }
  __syncthreads();

  const int c0 = 16 * g;
  float m[16];
  #pragma unroll
  for (int j = 0; j < 16; ++j) m[j] = 0.f;
  for (int hd = 0; hd < 128; ++hd){
    float tv = T[o * 129 + hd];
    const float* wq = w_qkv + (size_t)hd * 64 + c0;
    #pragma unroll
    for (int j = 0; j < 16; ++j) m[j] = fmaf(tv, wq[j], m[j]);
  }
  #pragma unroll
  for (int j = 0; j < 16; ++j) M[(size_t)b * 4096 + o * 64 + c0 + j] = m[j];
}

// ---------------------------------------------------------------------------
// kernO: out[b,o,n] = sum_c M_b[o][c] x[b,c,n] + b_out[o]
// ---------------------------------------------------------------------------
__global__ __launch_bounds__(256) void kernO(
    const float* __restrict__ x, const float* __restrict__ M,
    const float* __restrict__ b_out, float* __restrict__ out)
{
  const int blk = blockIdx.x;
  const int b   = blk / 320;
  const int pos = (blk % 320) * 256 + threadIdx.x;
  const float* xb = x + (size_t)b * 64 * N_POS + pos;

  float xr[64];
  #pragma unroll
  for (int c = 0; c < 64; ++c) xr[c] = xb[(size_t)c * N_POS];

  const float* Mb = M + (size_t)b * 4096;
  float* ob = out + (size_t)b * 64 * N_POS + pos;

  for (int o = 0; o < 64; ++o){
    const float* mr = Mb + o * 64;
    float a0 = b_out[o], a1 = 0.f, a2 = 0.f, a3 = 0.f;
    #pragma unroll
    for (int c4 = 0; c4 < 16; ++c4){
      a0 = fmaf(mr[4 * c4 + 0], xr[4 * c4 + 0], a0);
      a1 = fmaf(mr[4 * c4 + 1], xr[4 * c4 + 1], a1);
      a2 = fmaf(mr[4 * c4 + 2], xr[4 * c4 + 2], a2);
      a3 = fmaf(mr[4 * c4 + 3], xr[4 * c4 + 3], a3);
    }
    ob[(size_t)o * N_POS] = (a0 + a1) + (a2 + a3);
  }
}

// ---------------------------------------------------------------------------
extern "C" void kernel_launch(void* const* d_in, const int* in_sizes, int n_in,
                              void* d_out, int out_size, void* d_ws, size_t ws_size,
                              hipStream_t stream)
{
  const float* x     = (const float*)d_in[0];
  const float* w_qkv = (const float*)d_in[1];
  const float* w_out = (const float*)d_in[2];
  const float* b_out = (const float*)d_in[3];
  float* out = (float*)d_out;
  float* ws  = (float*)d_ws;

  static const int cand[] = {64, 40, 32, 20, 16, 10, 8, 5, 4, 2, 1};
  int nch = 1;
  for (int i = 0; i < 11; ++i){
    size_t need = ((size_t)8 * cand[i] * (8192 + 128)
                   + 8 * 8192 + 8 * 128 + (size_t)2 * 8 * 4096) * 4;
    if (need <= ws_size){ nch = cand[i]; break; }
  }
  const int tpc = TILES / nch;

  float* pA  = ws;
  float* pZ  = pA + (size_t)8 * nch * 8192;
  float* Ar  = pZ + (size_t)8 * nch * 128;
  float* Zr  = Ar + (size_t)8 * 8192;
  float* ctx = Zr + (size_t)8 * 128;
  float* M   = ctx + (size_t)8 * 4096;

  kernA<<<8 * nch, 256, 0, stream>>>(x, w_qkv, pA, pZ, nch, tpc);
  kernR1<<<64,     256, 0, stream>>>(pA, pZ, Ar, Zr, nch);
  kernR2<<<8,      256, 0, stream>>>(Ar, Zr, w_qkv, ctx);
  kernM<<<8,       256, 0, stream>>>(ctx, w_qkv, w_out, M);
  kernO<<<2560,    256, 0, stream>>>(x, M, b_out, out);
}

// Round 4
// 207.207 us; speedup vs baseline: 2.9199x; 1.6265x over previous
//
#include <hip/hip_runtime.h>
#include <stdint.h>

// LinearAttention. R3: kernO -> MFMA GEMM (M loaded once into fragments).
// Math: final[b,o,n] = sum_c M_b[o,c] x[b,c,n] + b_out[o]
//   M_b = W_out * blockdiag_h(ctx_h^T) * W_q
//   ctx[hd][e] = (1/Z[hd]) sum_c A[hd][c] Wv[32h+e][c]
//   A[hd][c]   = sum_n exp(k[hd,n]) x[c,n],  Z[hd] = sum_n exp(k[hd,n])
//   k[hd,n]    = sum_c Wk[hd][c] x[c,n]   (k ~ N(0,0.4^2): exp fp32-safe)

#define N_POS 81920   // 80*1024
#define NT    64      // positions per kernA tile
#define TILES 1280    // tiles per batch

typedef short bf16x8 __attribute__((ext_vector_type(8)));
typedef float f32x4  __attribute__((ext_vector_type(4)));

__device__ __forceinline__ uint32_t packbf(float lo, float hi){
  uint32_t a = __float_as_uint(lo), b = __float_as_uint(hi);
  a = (a + 0x8000u) >> 16;
  b = (b + 0x8000u) & 0xffff0000u;
  return a | b;
}
__device__ __forceinline__ short bf16of(float v){
  return (short)((__float_as_uint(v) + 0x8000u) >> 16);
}

// ---------------------------------------------------------------------------
// kernA: per (batch, chunk): partial A[128][64], Z[128] via MFMA.
// MFMA 16x16x32 layouts: A: row=l&15, k=(l>>4)*8+j (32-wide K-chunks);
//                        B: col=l&15, k=(l>>4)*8+j; D: col=l&15, row=(l>>4)*4+r
// ---------------------------------------------------------------------------
__global__ __launch_bounds__(256, 2) void kernA(
    const float* __restrict__ x, const float* __restrict__ w,
    float* __restrict__ pA, float* __restrict__ pZ, int nch, int tpc)
{
  __shared__ __align__(16) uint16_t xs_cp[64 * 72];
  __shared__ __align__(16) uint16_t xs_pc[64 * 72];
  __shared__ __align__(16) uint16_t es[128 * 72];

  const int t  = threadIdx.x;
  const int wv = t >> 6;     // wave 0..3
  const int l  = t & 63;
  const int lm = l & 15;     // fragment row/col
  const int lg = l >> 4;     // fragment k-group

  const int b  = blockIdx.x / nch;
  const int ch = blockIdx.x % nch;
  const float* xb = x + (size_t)b * 64 * N_POS;

  // Wk (w_qkv rows 128..255) as phase1 B-fragments, kept in registers.
  bf16x8 wkf[8][2];
  #pragma unroll
  for (int ht = 0; ht < 8; ++ht)
    #pragma unroll
    for (int kk = 0; kk < 2; ++kk){
      const float* wp = w + (size_t)(128 + 16*ht + lm) * 64 + 32*kk + 8*lg;
      float4 w0 = *(const float4*)wp;
      float4 w1 = *(const float4*)(wp + 4);
      bf16x8 f;
      f[0]=bf16of(w0.x); f[1]=bf16of(w0.y); f[2]=bf16of(w0.z); f[3]=bf16of(w0.w);
      f[4]=bf16of(w1.x); f[5]=bf16of(w1.y); f[6]=bf16of(w1.z); f[7]=bf16of(w1.w);
      wkf[ht][kk] = f;
    }

  bf16x8 ones;
  #pragma unroll
  for (int j = 0; j < 8; ++j) ones[j] = (short)0x3F80;   // bf16 1.0

  f32x4 acc[2][4], zac[2];
  #pragma unroll
  for (int m = 0; m < 2; ++m){
    zac[m] = (f32x4){0.f,0.f,0.f,0.f};
    #pragma unroll
    for (int n = 0; n < 4; ++n) acc[m][n] = (f32x4){0.f,0.f,0.f,0.f};
  }

  for (int tile = 0; tile < tpc; ++tile){
    const int n0 = (ch * tpc + tile) * NT;
    __syncthreads();   // prior phase2 done with xs_cp/es

    // stage xs_cp[c][pos]: row rr, 16-pos slice pc (coalesced 64B/row)
    {
      const int rr = t >> 2, pc = t & 3;
      const float* g = xb + (size_t)rr * N_POS + n0 + 16*pc;
      float4 a0 = *(const float4*)g;
      float4 a1 = *(const float4*)(g + 4);
      float4 a2 = *(const float4*)(g + 8);
      float4 a3 = *(const float4*)(g + 12);
      uint4 v0, v1;
      v0.x = packbf(a0.x,a0.y); v0.y = packbf(a0.z,a0.w);
      v0.z = packbf(a1.x,a1.y); v0.w = packbf(a1.z,a1.w);
      v1.x = packbf(a2.x,a2.y); v1.y = packbf(a2.z,a2.w);
      v1.z = packbf(a3.x,a3.y); v1.w = packbf(a3.z,a3.w);
      *(uint4*)&xs_cp[rr*72 + 16*pc]     = v0;
      *(uint4*)&xs_cp[rr*72 + 16*pc + 8] = v1;
    }
    // stage xs_pc[pos][c]: thread = one pos, 16 c (coalesced 256B per c)
    {
      const int pp = t & 63, c0 = (t >> 6) * 16;
      float v[16];
      #pragma unroll
      for (int i = 0; i < 16; ++i)
        v[i] = xb[(size_t)(c0 + i) * N_POS + n0 + pp];
      uint4 u0, u1;
      u0.x = packbf(v[0],v[1]);   u0.y = packbf(v[2],v[3]);
      u0.z = packbf(v[4],v[5]);   u0.w = packbf(v[6],v[7]);
      u1.x = packbf(v[8],v[9]);   u1.y = packbf(v[10],v[11]);
      u1.z = packbf(v[12],v[13]); u1.w = packbf(v[14],v[15]);
      *(uint4*)&xs_pc[pp*72 + c0]     = u0;
      *(uint4*)&xs_pc[pp*72 + c0 + 8] = u1;
    }
    __syncthreads();

    // phase1: wave wv owns pos-tile wv. S[pos][hd] -> E=exp -> es[hd][pos]
    {
      bf16x8 af0 = *(const bf16x8*)&xs_pc[(16*wv + lm)*72 + 8*lg];        // c 0..31
      bf16x8 af1 = *(const bf16x8*)&xs_pc[(16*wv + lm)*72 + 32 + 8*lg];   // c 32..63
      #pragma unroll
      for (int ht = 0; ht < 8; ++ht){
        f32x4 s = (f32x4){0.f,0.f,0.f,0.f};
        s = __builtin_amdgcn_mfma_f32_16x16x32_bf16(af0, wkf[ht][0], s, 0,0,0);
        s = __builtin_amdgcn_mfma_f32_16x16x32_bf16(af1, wkf[ht][1], s, 0,0,0);
        float e0 = __expf(s[0]), e1 = __expf(s[1]);
        float e2 = __expf(s[2]), e3 = __expf(s[3]);
        uint2 pk; pk.x = packbf(e0,e1); pk.y = packbf(e2,e3);
        *(uint2*)&es[(16*ht + lm)*72 + 16*wv + 4*lg] = pk;
      }
    }
    __syncthreads();

    // phase2: wave wv owns hd-tiles {2wv, 2wv+1} x all 4 c-tiles
    #pragma unroll
    for (int kk = 0; kk < 2; ++kk){
      bf16x8 ea[2], xbf[4];
      #pragma unroll
      for (int m = 0; m < 2; ++m)
        ea[m] = *(const bf16x8*)&es[(16*(2*wv+m) + lm)*72 + 32*kk + 8*lg];
      #pragma unroll
      for (int n = 0; n < 4; ++n)
        xbf[n] = *(const bf16x8*)&xs_cp[(16*n + lm)*72 + 32*kk + 8*lg];
      #pragma unroll
      for (int m = 0; m < 2; ++m){
        #pragma unroll
        for (int n = 0; n < 4; ++n)
          acc[m][n] = __builtin_amdgcn_mfma_f32_16x16x32_bf16(ea[m], xbf[n], acc[m][n], 0,0,0);
        zac[m] = __builtin_amdgcn_mfma_f32_16x16x32_bf16(ea[m], ones, zac[m], 0,0,0);
      }
    }
  }

  // epilogue: D-layout row hd = 16(2wv+m)+4lg+r, col c = 16n+lm
  float* pa = pA + (size_t)blockIdx.x * 8192;
  #pragma unroll
  for (int m = 0; m < 2; ++m){
    const int hd0 = 16*(2*wv + m) + 4*lg;
    #pragma unroll
    for (int n = 0; n < 4; ++n)
      #pragma unroll
      for (int r = 0; r < 4; ++r)
        pa[(size_t)(hd0 + r)*64 + 16*n + lm] = acc[m][n][r];
    if (lm == 0){
      #pragma unroll
      for (int r = 0; r < 4; ++r)
        pZ[(size_t)blockIdx.x * 128 + hd0 + r] = zac[m][r];
    }
  }
}

// ---------------------------------------------------------------------------
// kernR1: parallel reduce of partials. grid 64 = 8 batches x 8 slices.
// ---------------------------------------------------------------------------
__global__ __launch_bounds__(256) void kernR1(
    const float* __restrict__ pA, const float* __restrict__ pZ,
    float* __restrict__ Ar, float* __restrict__ Zr, int nch)
{
  const int b = blockIdx.x >> 3, s = blockIdx.x & 7;
  const int off = s * 1024 + threadIdx.x * 4;
  float4 a = make_float4(0.f, 0.f, 0.f, 0.f);
  for (int ch = 0; ch < nch; ++ch){
    float4 v = *(const float4*)&pA[(size_t)(b * nch + ch) * 8192 + off];
    a.x += v.x; a.y += v.y; a.z += v.z; a.w += v.w;
  }
  *(float4*)&Ar[(size_t)b * 8192 + off] = a;
  if (s == 0 && threadIdx.x < 128){
    float z = 0.f;
    for (int ch = 0; ch < nch; ++ch) z += pZ[(size_t)(b * nch + ch) * 128 + threadIdx.x];
    Zr[b * 128 + threadIdx.x] = z;
  }
}

// ---------------------------------------------------------------------------
// kernR2: per batch: ctx[hd][e] = (A[hd]·Wv[e]) / Z[hd]
// ---------------------------------------------------------------------------
__global__ __launch_bounds__(256) void kernR2(
    const float* __restrict__ Ar, const float* __restrict__ Zr,
    const float* __restrict__ w, float* __restrict__ ctx)
{
  __shared__ float A[128 * 65];
  __shared__ float Z[128];
  const int b = blockIdx.x, t = threadIdx.x;

  #pragma unroll
  for (int k = 0; k < 32; ++k){
    int i = t + 256 * k;
    A[(i >> 6) * 65 + (i & 63)] = Ar[(size_t)b * 8192 + i];
  }
  if (t < 128) Z[t] = Zr[b * 128 + t];
  __syncthreads();

  const int hd = t & 127, h = hd >> 5, e0 = (t >> 7) * 16;
  const float rz = 1.0f / Z[hd];
  for (int je = 0; je < 16; ++je){
    int e = e0 + je;
    const float* wv = w + (size_t)(256 + 32 * h + e) * 64;   // Wv row
    float a = 0.f;
    #pragma unroll
    for (int c = 0; c < 64; ++c) a = fmaf(A[hd * 65 + c], wv[c], a);
    ctx[((size_t)b * 128 + hd) * 32 + e] = a * rz;
  }
}

// ---------------------------------------------------------------------------
// kernM: per batch: T[o][hd] = sum_e w_out[o][32h+e] ctx[hd][e];
//        M[o][c] = sum_hd T[o][hd] Wq[hd][c]
// ---------------------------------------------------------------------------
__global__ __launch_bounds__(256) void kernM(
    const float* __restrict__ ctx, const float* __restrict__ w_qkv,
    const float* __restrict__ w_out, float* __restrict__ M)
{
  __shared__ float cs[128 * 33];
  __shared__ float T[64 * 129];
  const int b = blockIdx.x, t = threadIdx.x;

  #pragma unroll
  for (int k = 0; k < 16; ++k){
    int i = t + 256 * k;
    cs[(i >> 5) * 33 + (i & 31)] = ctx[(size_t)b * 4096 + i];
  }
  __syncthreads();

  const int o = t & 63, g = t >> 6;
  for (int jh = 0; jh < 32; ++jh){
    int hd = 32 * g + jh, h = g;
    const float* wo = w_out + (size_t)o * 128 + 32 * h;
    float a = 0.f;
    #pragma unroll
    for (int e = 0; e < 32; ++e) a = fmaf(wo[e], cs[hd * 33 + e], a);
    T[o * 129 + hd] = a;
  }
  __syncthreads();

  const int c0 = 16 * g;
  float m[16];
  #pragma unroll
  for (int j = 0; j < 16; ++j) m[j] = 0.f;
  for (int hd = 0; hd < 128; ++hd){
    float tv = T[o * 129 + hd];
    const float* wq = w_qkv + (size_t)hd * 64 + c0;
    #pragma unroll
    for (int j = 0; j < 16; ++j) m[j] = fmaf(tv, wq[j], m[j]);
  }
  #pragma unroll
  for (int j = 0; j < 16; ++j) M[(size_t)b * 4096 + o * 64 + c0 + j] = m[j];
}

// ---------------------------------------------------------------------------
// kernO (MFMA): per block: out[64, 256-pos tile] = M_b * x + b_out.
// M in B-fragments (VGPRs, loaded once); x staged [pos][c] bf16 in LDS via
// strided-coalesced reads; D gives lane 4 consecutive pos -> dwordx4 stores.
// ---------------------------------------------------------------------------
__global__ __launch_bounds__(256, 2) void kernO(
    const float* __restrict__ x, const float* __restrict__ M,
    const float* __restrict__ b_out, float* __restrict__ out)
{
  __shared__ __align__(16) uint16_t xs[256 * 72];   // [pos][c], 36 KB

  const int t  = threadIdx.x;
  const int wv = t >> 6;
  const int l  = t & 63;
  const int lm = l & 15;
  const int lg = l >> 4;

  const int b  = blockIdx.x / 320;
  const int p0 = (blockIdx.x % 320) * 256;
  const float* xb = x + (size_t)b * 64 * N_POS + p0;

  // B-fragments of M: mb[ot][kk] -> lane holds M[16ot+lm][32kk+8lg+j]
  const float* Mb = M + (size_t)b * 4096;
  bf16x8 mb[4][2];
  float bias[4];
  #pragma unroll
  for (int ot = 0; ot < 4; ++ot){
    bias[ot] = b_out[16*ot + lm];
    #pragma unroll
    for (int kk = 0; kk < 2; ++kk){
      const float* mp = Mb + (size_t)(16*ot + lm)*64 + 32*kk + 8*lg;
      float4 m0 = *(const float4*)mp;
      float4 m1 = *(const float4*)(mp + 4);
      bf16x8 f;
      f[0]=bf16of(m0.x); f[1]=bf16of(m0.y); f[2]=bf16of(m0.z); f[3]=bf16of(m0.w);
      f[4]=bf16of(m1.x); f[5]=bf16of(m1.y); f[6]=bf16of(m1.z); f[7]=bf16of(m1.w);
      mb[ot][kk] = f;
    }
  }

  // stage xs[pos][c]: thread = one pos; per c coalesced 256B across lanes
  #pragma unroll
  for (int cc = 0; cc < 8; ++cc){
    float v[8];
    #pragma unroll
    for (int j = 0; j < 8; ++j)
      v[j] = xb[(size_t)(8*cc + j) * N_POS + t];
    uint4 u;
    u.x = packbf(v[0],v[1]); u.y = packbf(v[2],v[3]);
    u.z = packbf(v[4],v[5]); u.w = packbf(v[6],v[7]);
    *(uint4*)&xs[t*72 + 8*cc] = u;
  }
  __syncthreads();

  float* ob = out + (size_t)b * 64 * N_POS + p0;

  // wave wv: pos-tiles 4wv .. 4wv+3
  #pragma unroll
  for (int ip = 0; ip < 4; ++ip){
    const int pt = 4*wv + ip;
    bf16x8 af0 = *(const bf16x8*)&xs[(16*pt + lm)*72 + 8*lg];        // c 0..31
    bf16x8 af1 = *(const bf16x8*)&xs[(16*pt + lm)*72 + 32 + 8*lg];   // c 32..63
    #pragma unroll
    for (int ot = 0; ot < 4; ++ot){
      f32x4 d = (f32x4){0.f,0.f,0.f,0.f};
      d = __builtin_amdgcn_mfma_f32_16x16x32_bf16(af0, mb[ot][0], d, 0,0,0);
      d = __builtin_amdgcn_mfma_f32_16x16x32_bf16(af1, mb[ot][1], d, 0,0,0);
      // lane: o = 16ot+lm, pos = 16pt + 4lg + r (r=0..3 contiguous)
      float4 st = make_float4(d[0]+bias[ot], d[1]+bias[ot],
                              d[2]+bias[ot], d[3]+bias[ot]);
      *(float4*)&ob[(size_t)(16*ot + lm) * N_POS + 16*pt + 4*lg] = st;
    }
  }
}

// ---------------------------------------------------------------------------
extern "C" void kernel_launch(void* const* d_in, const int* in_sizes, int n_in,
                              void* d_out, int out_size, void* d_ws, size_t ws_size,
                              hipStream_t stream)
{
  const float* x     = (const float*)d_in[0];
  const float* w_qkv = (const float*)d_in[1];
  const float* w_out = (const float*)d_in[2];
  const float* b_out = (const float*)d_in[3];
  float* out = (float*)d_out;
  float* ws  = (float*)d_ws;

  static const int cand[] = {64, 40, 32, 20, 16, 10, 8, 5, 4, 2, 1};
  int nch = 1;
  for (int i = 0; i < 11; ++i){
    size_t need = ((size_t)8 * cand[i] * (8192 + 128)
                   + 8 * 8192 + 8 * 128 + (size_t)2 * 8 * 4096) * 4;
    if (need <= ws_size){ nch = cand[i]; break; }
  }
  const int tpc = TILES / nch;

  float* pA  = ws;
  float* pZ  = pA + (size_t)8 * nch * 8192;
  float* Ar  = pZ + (size_t)8 * nch * 128;
  float* Zr  = Ar + (size_t)8 * 8192;
  float* ctx = Zr + (size_t)8 * 128;
  float* M   = ctx + (size_t)8 * 4096;

  kernA<<<8 * nch, 256, 0, stream>>>(x, w_qkv, pA, pZ, nch, tpc);
  kernR1<<<64,     256, 0, stream>>>(pA, pZ, Ar, Zr, nch);
  kernR2<<<8,      256, 0, stream>>>(Ar, Zr, w_qkv, ctx);
  kernM<<<8,       256, 0, stream>>>(ctx, w_qkv, w_out, M);
  kernO<<<2560,    256, 0, stream>>>(x, M, b_out, out);
}

// Round 5
// 204.069 us; speedup vs baseline: 2.9648x; 1.0154x over previous
//
#include <hip/hip_runtime.h>
#include <stdint.h>

// LinearAttention. R4: kernA -> 512thr 8-wave with async-staged prefetch;
// kernR2+kernM fused.
// Math: final[b,o,n] = sum_c M_b[o,c] x[b,c,n] + b_out[o]
//   M_b = W_out * blockdiag_h(ctx_h^T) * W_q
//   ctx[hd][e] = (1/Z[hd]) sum_c A[hd][c] Wv[32h+e][c]
//   A[hd][c]   = sum_n exp(k[hd,n]) x[c,n],  Z[hd] = sum_n exp(k[hd,n])
//   k[hd,n]    = sum_c Wk[hd][c] x[c,n]   (k ~ N(0,0.4^2): exp fp32-safe)

#define N_POS 81920   // 80*1024
#define NT    64      // positions per kernA tile
#define TILES 1280    // tiles per batch

typedef short bf16x8 __attribute__((ext_vector_type(8)));
typedef float f32x4  __attribute__((ext_vector_type(4)));

__device__ __forceinline__ uint32_t packbf(float lo, float hi){
  uint32_t a = __float_as_uint(lo), b = __float_as_uint(hi);
  a = (a + 0x8000u) >> 16;
  b = (b + 0x8000u) & 0xffff0000u;
  return a | b;
}
__device__ __forceinline__ short bf16of(float v){
  return (short)((__float_as_uint(v) + 0x8000u) >> 16);
}

// ---------------------------------------------------------------------------
// kernA: per (batch, chunk): partial A[128][64], Z[128] via MFMA.
// 512 threads = 8 waves. Per tile (64 pos):
//   stage xs_cp[c][pos] + xs_pc[pos][c] (bf16, pitch 72), prefetched 1 tile
//   ahead (issue loads after write-barrier, consume next iteration).
//   phase1: wave w: pos-tile w&3, ht range 4*(w>>2)..+3 -> es[hd][pos]
//   phase2: wave w: hd-tile w (rows 16w..16w+15), all 4 c-tiles + Z(ones)
// MFMA 16x16x32 layouts: A: row=l&15, k=(l>>4)*8+j (32-wide K-chunks);
//                        B: col=l&15, k=(l>>4)*8+j; D: col=l&15, row=(l>>4)*4+r
// ---------------------------------------------------------------------------
__global__ __launch_bounds__(512, 4) void kernA(
    const float* __restrict__ x, const float* __restrict__ w,
    float* __restrict__ pA, float* __restrict__ pZ, int nch, int tpc)
{
  __shared__ __align__(16) uint16_t xs_cp[64 * 72];   // [c][pos]
  __shared__ __align__(16) uint16_t xs_pc[64 * 72];   // [pos][c]
  __shared__ __align__(16) uint16_t es[128 * 72];     // [hd][pos]

  const int t  = threadIdx.x;
  const int w8 = t >> 6;     // wave 0..7
  const int l  = t & 63;
  const int lm = l & 15;
  const int lg = l >> 4;

  const int b  = blockIdx.x / nch;
  const int ch = blockIdx.x % nch;
  const float* xb = x + (size_t)b * 64 * N_POS;

  // staging roles
  const int sc  = t >> 3;    // xs_cp: c row
  const int spg = t & 7;     // xs_cp: pos-group (8 pos)
  const int spp = t & 63;    // xs_pc: pos
  const int scg = t >> 6;    // xs_pc: c-group (8 c)

  // phase1 split
  const int pt  = w8 & 3;          // pos-tile
  const int ht0 = (w8 >> 2) * 4;   // first hd-tile of 4

  // Wk B-fragments for ht0..ht0+3 (w_qkv rows 128..255)
  bf16x8 wkf[4][2];
  #pragma unroll
  for (int i = 0; i < 4; ++i)
    #pragma unroll
    for (int kk = 0; kk < 2; ++kk){
      const float* wp = w + (size_t)(128 + 16*(ht0+i) + lm) * 64 + 32*kk + 8*lg;
      float4 w0 = *(const float4*)wp;
      float4 w1 = *(const float4*)(wp + 4);
      bf16x8 f;
      f[0]=bf16of(w0.x); f[1]=bf16of(w0.y); f[2]=bf16of(w0.z); f[3]=bf16of(w0.w);
      f[4]=bf16of(w1.x); f[5]=bf16of(w1.y); f[6]=bf16of(w1.z); f[7]=bf16of(w1.w);
      wkf[i][kk] = f;
    }

  bf16x8 ones;
  #pragma unroll
  for (int j = 0; j < 8; ++j) ones[j] = (short)0x3F80;   // bf16 1.0

  f32x4 acc[4], zac;
  zac = (f32x4){0.f,0.f,0.f,0.f};
  #pragma unroll
  for (int n = 0; n < 4; ++n) acc[n] = (f32x4){0.f,0.f,0.f,0.f};

  // prefetch tile 0
  float4 f0, f1;
  float v[8];
  {
    const int n0 = (ch * tpc) * NT;
    const float* ga = xb + (size_t)sc * N_POS + n0 + 8*spg;
    f0 = *(const float4*)ga;
    f1 = *(const float4*)(ga + 4);
    const float* gb = xb + (size_t)(8*scg) * N_POS + n0 + spp;
    #pragma unroll
    for (int i = 0; i < 8; ++i) v[i] = gb[(size_t)i * N_POS];
  }

  for (int tile = 0; tile < tpc; ++tile){
    __syncthreads();   // prev phase2 done with xs_cp/es
    // write staged tile to LDS (vmcnt waits auto-inserted)
    {
      uint4 u;
      u.x = packbf(f0.x,f0.y); u.y = packbf(f0.z,f0.w);
      u.z = packbf(f1.x,f1.y); u.w = packbf(f1.z,f1.w);
      *(uint4*)&xs_cp[sc*72 + 8*spg] = u;
      uint4 u2;
      u2.x = packbf(v[0],v[1]); u2.y = packbf(v[2],v[3]);
      u2.z = packbf(v[4],v[5]); u2.w = packbf(v[6],v[7]);
      *(uint4*)&xs_pc[spp*72 + 8*scg] = u2;
    }
    __syncthreads();
    // issue next tile's loads (hide HBM latency under phase1+phase2)
    if (tile + 1 < tpc){
      const int n1 = (ch * tpc + tile + 1) * NT;
      const float* ga = xb + (size_t)sc * N_POS + n1 + 8*spg;
      f0 = *(const float4*)ga;
      f1 = *(const float4*)(ga + 4);
      const float* gb = xb + (size_t)(8*scg) * N_POS + n1 + spp;
      #pragma unroll
      for (int i = 0; i < 8; ++i) v[i] = gb[(size_t)i * N_POS];
    }
    // phase1: S[pos][hd] -> E=exp -> es[hd][pos]
    {
      bf16x8 af0 = *(const bf16x8*)&xs_pc[(16*pt + lm)*72 + 8*lg];        // c 0..31
      bf16x8 af1 = *(const bf16x8*)&xs_pc[(16*pt + lm)*72 + 32 + 8*lg];   // c 32..63
      #pragma unroll
      for (int i = 0; i < 4; ++i){
        f32x4 s = (f32x4){0.f,0.f,0.f,0.f};
        s = __builtin_amdgcn_mfma_f32_16x16x32_bf16(af0, wkf[i][0], s, 0,0,0);
        s = __builtin_amdgcn_mfma_f32_16x16x32_bf16(af1, wkf[i][1], s, 0,0,0);
        // lane: pos = 16pt+4lg+r, hd = 16(ht0+i)+lm
        float e0 = __expf(s[0]), e1 = __expf(s[1]);
        float e2 = __expf(s[2]), e3 = __expf(s[3]);
        uint2 pk; pk.x = packbf(e0,e1); pk.y = packbf(e2,e3);
        *(uint2*)&es[(16*(ht0+i) + lm)*72 + 16*pt + 4*lg] = pk;
      }
    }
    __syncthreads();
    // phase2: wave w8 owns hd rows 16w8..16w8+15
    #pragma unroll
    for (int kk = 0; kk < 2; ++kk){
      bf16x8 ea = *(const bf16x8*)&es[(16*w8 + lm)*72 + 32*kk + 8*lg];
      bf16x8 xbf[4];
      #pragma unroll
      for (int n = 0; n < 4; ++n)
        xbf[n] = *(const bf16x8*)&xs_cp[(16*n + lm)*72 + 32*kk + 8*lg];
      #pragma unroll
      for (int n = 0; n < 4; ++n)
        acc[n] = __builtin_amdgcn_mfma_f32_16x16x32_bf16(ea, xbf[n], acc[n], 0,0,0);
      zac = __builtin_amdgcn_mfma_f32_16x16x32_bf16(ea, ones, zac, 0,0,0);
    }
  }

  // epilogue: D-layout row hd = 16w8+4lg+r, col c = 16n+lm
  float* pa = pA + (size_t)blockIdx.x * 8192;
  const int hd0 = 16*w8 + 4*lg;
  #pragma unroll
  for (int n = 0; n < 4; ++n)
    #pragma unroll
    for (int r = 0; r < 4; ++r)
      pa[(size_t)(hd0 + r)*64 + 16*n + lm] = acc[n][r];
  if (lm == 0){
    #pragma unroll
    for (int r = 0; r < 4; ++r)
      pZ[(size_t)blockIdx.x * 128 + hd0 + r] = zac[r];
  }
}

// ---------------------------------------------------------------------------
// kernR1: parallel reduce of partials. grid 64 = 8 batches x 8 slices.
// ---------------------------------------------------------------------------
__global__ __launch_bounds__(256) void kernR1(
    const float* __restrict__ pA, const float* __restrict__ pZ,
    float* __restrict__ Ar, float* __restrict__ Zr, int nch)
{
  const int b = blockIdx.x >> 3, s = blockIdx.x & 7;
  const int off = s * 1024 + threadIdx.x * 4;
  float4 a = make_float4(0.f, 0.f, 0.f, 0.f);
  for (int ch = 0; ch < nch; ++ch){
    float4 v = *(const float4*)&pA[(size_t)(b * nch + ch) * 8192 + off];
    a.x += v.x; a.y += v.y; a.z += v.z; a.w += v.w;
  }
  *(float4*)&Ar[(size_t)b * 8192 + off] = a;
  if (s == 0 && threadIdx.x < 128){
    float z = 0.f;
    for (int ch = 0; ch < nch; ++ch) z += pZ[(size_t)(b * nch + ch) * 128 + threadIdx.x];
    Zr[b * 128 + threadIdx.x] = z;
  }
}

// ---------------------------------------------------------------------------
// kernCM (fused R2+M): per batch:
//   ctx[hd][e] = (A[hd]·Wv[e]) / Z[hd]        (-> LDS cs)
//   T[o][hd] = sum_e w_out[o][32h+e] cs[hd][e]
//   M[o][c]  = sum_hd T[o][hd] Wq[hd][c]
// ---------------------------------------------------------------------------
__global__ __launch_bounds__(256) void kernCM(
    const float* __restrict__ Ar, const float* __restrict__ Zr,
    const float* __restrict__ w_qkv, const float* __restrict__ w_out,
    float* __restrict__ M)
{
  __shared__ float A[128 * 65];
  __shared__ float Z[128];
  __shared__ float cs[128 * 33];
  __shared__ float T[64 * 129];
  const int b = blockIdx.x, t = threadIdx.x;

  #pragma unroll
  for (int k = 0; k < 32; ++k){
    int i = t + 256 * k;
    A[(i >> 6) * 65 + (i & 63)] = Ar[(size_t)b * 8192 + i];
  }
  if (t < 128) Z[t] = Zr[b * 128 + t];
  __syncthreads();

  {
    const int hd = t & 127, h = hd >> 5, e0 = (t >> 7) * 16;
    const float rz = 1.0f / Z[hd];
    for (int je = 0; je < 16; ++je){
      int e = e0 + je;
      const float* wv = w_qkv + (size_t)(256 + 32 * h + e) * 64;   // Wv row
      float a = 0.f;
      #pragma unroll
      for (int c = 0; c < 64; ++c) a = fmaf(A[hd * 65 + c], wv[c], a);
      cs[hd * 33 + e] = a * rz;
    }
  }
  __syncthreads();

  const int o = t & 63, g = t >> 6;
  for (int jh = 0; jh < 32; ++jh){
    int hd = 32 * g + jh;
    const float* wo = w_out + (size_t)o * 128 + 32 * g;
    float a = 0.f;
    #pragma unroll
    for (int e = 0; e < 32; ++e) a = fmaf(wo[e], cs[hd * 33 + e], a);
    T[o * 129 + hd] = a;
  }
  __syncthreads();

  const int c0 = 16 * g;
  float m[16];
  #pragma unroll
  for (int j = 0; j < 16; ++j) m[j] = 0.f;
  for (int hd = 0; hd < 128; ++hd){
    float tv = T[o * 129 + hd];
    const float* wq = w_qkv + (size_t)hd * 64 + c0;
    #pragma unroll
    for (int j = 0; j < 16; ++j) m[j] = fmaf(tv, wq[j], m[j]);
  }
  #pragma unroll
  for (int j = 0; j < 16; ++j) M[(size_t)b * 4096 + o * 64 + c0 + j] = m[j];
}

// ---------------------------------------------------------------------------
// kernO (MFMA): per block: out[64, 256-pos tile] = M_b * x + b_out.
// ---------------------------------------------------------------------------
__global__ __launch_bounds__(256, 2) void kernO(
    const float* __restrict__ x, const float* __restrict__ M,
    const float* __restrict__ b_out, float* __restrict__ out)
{
  __shared__ __align__(16) uint16_t xs[256 * 72];   // [pos][c], 36 KB

  const int t  = threadIdx.x;
  const int wv = t >> 6;
  const int l  = t & 63;
  const int lm = l & 15;
  const int lg = l >> 4;

  const int b  = blockIdx.x / 320;
  const int p0 = (blockIdx.x % 320) * 256;
  const float* xb = x + (size_t)b * 64 * N_POS + p0;

  // B-fragments of M: mb[ot][kk] -> lane holds M[16ot+lm][32kk+8lg+j]
  const float* Mb = M + (size_t)b * 4096;
  bf16x8 mb[4][2];
  float bias[4];
  #pragma unroll
  for (int ot = 0; ot < 4; ++ot){
    bias[ot] = b_out[16*ot + lm];
    #pragma unroll
    for (int kk = 0; kk < 2; ++kk){
      const float* mp = Mb + (size_t)(16*ot + lm)*64 + 32*kk + 8*lg;
      float4 m0 = *(const float4*)mp;
      float4 m1 = *(const float4*)(mp + 4);
      bf16x8 f;
      f[0]=bf16of(m0.x); f[1]=bf16of(m0.y); f[2]=bf16of(m0.z); f[3]=bf16of(m0.w);
      f[4]=bf16of(m1.x); f[5]=bf16of(m1.y); f[6]=bf16of(m1.z); f[7]=bf16of(m1.w);
      mb[ot][kk] = f;
    }
  }

  // stage xs[pos][c]: thread = one pos; per c coalesced across lanes
  #pragma unroll
  for (int cc = 0; cc < 8; ++cc){
    float v[8];
    #pragma unroll
    for (int j = 0; j < 8; ++j)
      v[j] = xb[(size_t)(8*cc + j) * N_POS + t];
    uint4 u;
    u.x = packbf(v[0],v[1]); u.y = packbf(v[2],v[3]);
    u.z = packbf(v[4],v[5]); u.w = packbf(v[6],v[7]);
    *(uint4*)&xs[t*72 + 8*cc] = u;
  }
  __syncthreads();

  float* ob = out + (size_t)b * 64 * N_POS + p0;

  // wave wv: pos-tiles 4wv .. 4wv+3
  #pragma unroll
  for (int ip = 0; ip < 4; ++ip){
    const int pt = 4*wv + ip;
    bf16x8 af0 = *(const bf16x8*)&xs[(16*pt + lm)*72 + 8*lg];        // c 0..31
    bf16x8 af1 = *(const bf16x8*)&xs[(16*pt + lm)*72 + 32 + 8*lg];   // c 32..63
    #pragma unroll
    for (int ot = 0; ot < 4; ++ot){
      f32x4 d = (f32x4){0.f,0.f,0.f,0.f};
      d = __builtin_amdgcn_mfma_f32_16x16x32_bf16(af0, mb[ot][0], d, 0,0,0);
      d = __builtin_amdgcn_mfma_f32_16x16x32_bf16(af1, mb[ot][1], d, 0,0,0);
      // lane: o = 16ot+lm, pos = 16pt + 4lg + r (r=0..3 contiguous)
      float4 st = make_float4(d[0]+bias[ot], d[1]+bias[ot],
                              d[2]+bias[ot], d[3]+bias[ot]);
      *(float4*)&ob[(size_t)(16*ot + lm) * N_POS + 16*pt + 4*lg] = st;
    }
  }
}

// ---------------------------------------------------------------------------
extern "C" void kernel_launch(void* const* d_in, const int* in_sizes, int n_in,
                              void* d_out, int out_size, void* d_ws, size_t ws_size,
                              hipStream_t stream)
{
  const float* x     = (const float*)d_in[0];
  const float* w_qkv = (const float*)d_in[1];
  const float* w_out = (const float*)d_in[2];
  const float* b_out = (const float*)d_in[3];
  float* out = (float*)d_out;
  float* ws  = (float*)d_ws;

  static const int cand[] = {64, 40, 32, 20, 16, 10, 8, 5, 4, 2, 1};
  int nch = 1;
  for (int i = 0; i < 11; ++i){
    size_t need = ((size_t)8 * cand[i] * (8192 + 128)
                   + 8 * 8192 + 8 * 128 + (size_t)8 * 4096) * 4;
    if (need <= ws_size){ nch = cand[i]; break; }
  }
  const int tpc = TILES / nch;

  float* pA  = ws;
  float* pZ  = pA + (size_t)8 * nch * 8192;
  float* Ar  = pZ + (size_t)8 * nch * 128;
  float* Zr  = Ar + (size_t)8 * 8192;
  float* M   = Zr + (size_t)8 * 128;

  kernA<<<8 * nch, 512, 0, stream>>>(x, w_qkv, pA, pZ, nch, tpc);
  kernR1<<<64,     256, 0, stream>>>(pA, pZ, Ar, Zr, nch);
  kernCM<<<8,      256, 0, stream>>>(Ar, Zr, w_qkv, w_out, M);
  kernO<<<2560,    256, 0, stream>>>(x, M, b_out, out);
}

// Round 6
// 204.038 us; speedup vs baseline: 2.9652x; 1.0002x over previous
//
#include <hip/hip_runtime.h>
#include <stdint.h>

// LinearAttention. R5: kernA NT=128 (half the barriers), setprio on phase2;
// kernO at 4 blocks/CU.
// Math: final[b,o,n] = sum_c M_b[o,c] x[b,c,n] + b_out[o]
//   M_b = W_out * blockdiag_h(ctx_h^T) * W_q
//   ctx[hd][e] = (1/Z[hd]) sum_c A[hd][c] Wv[32h+e][c]
//   A[hd][c]   = sum_n exp(k[hd,n]) x[c,n],  Z[hd] = sum_n exp(k[hd,n])
//   k[hd,n]    = sum_c Wk[hd][c] x[c,n]   (k ~ N(0,0.4^2): exp fp32-safe)

#define N_POS 81920   // 80*1024
#define NT    128     // positions per kernA tile
#define TILES 640     // tiles per batch

typedef short bf16x8 __attribute__((ext_vector_type(8)));
typedef float f32x4  __attribute__((ext_vector_type(4)));

__device__ __forceinline__ uint32_t packbf(float lo, float hi){
  uint32_t a = __float_as_uint(lo), b = __float_as_uint(hi);
  a = (a + 0x8000u) >> 16;
  b = (b + 0x8000u) & 0xffff0000u;
  return a | b;
}
__device__ __forceinline__ short bf16of(float v){
  return (short)((__float_as_uint(v) + 0x8000u) >> 16);
}

// ---------------------------------------------------------------------------
// kernA: per (batch, chunk): partial A[128][64], Z[128] via MFMA.
// 512 threads = 8 waves, tile = 128 pos.
//   stage xs_cp[c][pos] (pitch 136) + xs_pc[pos][c] (pitch 72), prefetched
//   1 tile ahead. es[hd][pos] (pitch 136).
//   phase1: wave w: pos-tiles {w&3, (w&3)+4}, ht 4*(w>>2)..+3 -> es
//   phase2: wave w: hd-tile w (16 hd), K=128 pos in 4 chunks
// MFMA 16x16x32: A: row=l&15, k=(l>>4)*8+j (32-wide K-chunks);
//                B: col=l&15, k=(l>>4)*8+j; D: col=l&15, row=(l>>4)*4+r
// ---------------------------------------------------------------------------
__global__ __launch_bounds__(512, 4) void kernA(
    const float* __restrict__ x, const float* __restrict__ w,
    float* __restrict__ pA, float* __restrict__ pZ, int nch, int tpc)
{
  __shared__ __align__(16) uint16_t xs_cp[64 * 136];   // [c][pos]
  __shared__ __align__(16) uint16_t xs_pc[128 * 72];   // [pos][c]
  __shared__ __align__(16) uint16_t es[128 * 136];     // [hd][pos]

  const int t  = threadIdx.x;
  const int w8 = t >> 6;     // wave 0..7
  const int l  = t & 63;
  const int lm = l & 15;
  const int lg = l >> 4;

  const int b  = blockIdx.x / nch;
  const int ch = blockIdx.x % nch;
  const float* xb = x + (size_t)b * 64 * N_POS;

  // staging roles
  const int rr  = t >> 3;        // xs_cp: c row 0..63
  const int pg  = t & 7;         // xs_cp: 16-pos group
  const int spp = t & 127;       // xs_pc: pos
  const int scg = t >> 7;        // xs_pc: c-group (16 c)

  // phase1 split: 2 pos-tiles x 4 ht per wave
  const int pth = w8 & 3;
  const int ht0 = (w8 >> 2) * 4;

  // Wk B-fragments for ht0..ht0+3 (w_qkv rows 128..255)
  bf16x8 wkf[4][2];
  #pragma unroll
  for (int i = 0; i < 4; ++i)
    #pragma unroll
    for (int kk = 0; kk < 2; ++kk){
      const float* wp = w + (size_t)(128 + 16*(ht0+i) + lm) * 64 + 32*kk + 8*lg;
      float4 w0 = *(const float4*)wp;
      float4 w1 = *(const float4*)(wp + 4);
      bf16x8 f;
      f[0]=bf16of(w0.x); f[1]=bf16of(w0.y); f[2]=bf16of(w0.z); f[3]=bf16of(w0.w);
      f[4]=bf16of(w1.x); f[5]=bf16of(w1.y); f[6]=bf16of(w1.z); f[7]=bf16of(w1.w);
      wkf[i][kk] = f;
    }

  bf16x8 ones;
  #pragma unroll
  for (int j = 0; j < 8; ++j) ones[j] = (short)0x3F80;   // bf16 1.0

  f32x4 acc[4], zac;
  zac = (f32x4){0.f,0.f,0.f,0.f};
  #pragma unroll
  for (int n = 0; n < 4; ++n) acc[n] = (f32x4){0.f,0.f,0.f,0.f};

  // prefetch tile 0
  float4 fa0, fa1, fa2, fa3;
  float v[16];
  {
    const int n0 = (ch * tpc) * NT;
    const float* ga = xb + (size_t)rr * N_POS + n0 + 16*pg;
    fa0 = *(const float4*)ga;       fa1 = *(const float4*)(ga + 4);
    fa2 = *(const float4*)(ga + 8); fa3 = *(const float4*)(ga + 12);
    const float* gb = xb + (size_t)(16*scg) * N_POS + n0 + spp;
    #pragma unroll
    for (int i = 0; i < 16; ++i) v[i] = gb[(size_t)i * N_POS];
  }

  for (int tile = 0; tile < tpc; ++tile){
    __syncthreads();   // prev phase2 done with xs_cp/es
    // write staged tile to LDS
    {
      uint4 u0, u1;
      u0.x = packbf(fa0.x,fa0.y); u0.y = packbf(fa0.z,fa0.w);
      u0.z = packbf(fa1.x,fa1.y); u0.w = packbf(fa1.z,fa1.w);
      u1.x = packbf(fa2.x,fa2.y); u1.y = packbf(fa2.z,fa2.w);
      u1.z = packbf(fa3.x,fa3.y); u1.w = packbf(fa3.z,fa3.w);
      *(uint4*)&xs_cp[rr*136 + 16*pg]     = u0;
      *(uint4*)&xs_cp[rr*136 + 16*pg + 8] = u1;
      uint4 p0, p1;
      p0.x = packbf(v[0],v[1]);   p0.y = packbf(v[2],v[3]);
      p0.z = packbf(v[4],v[5]);   p0.w = packbf(v[6],v[7]);
      p1.x = packbf(v[8],v[9]);   p1.y = packbf(v[10],v[11]);
      p1.z = packbf(v[12],v[13]); p1.w = packbf(v[14],v[15]);
      *(uint4*)&xs_pc[spp*72 + 16*scg]     = p0;
      *(uint4*)&xs_pc[spp*72 + 16*scg + 8] = p1;
    }
    __syncthreads();
    // issue next tile's loads (hide HBM latency under phase1+phase2)
    if (tile + 1 < tpc){
      const int n1 = (ch * tpc + tile + 1) * NT;
      const float* ga = xb + (size_t)rr * N_POS + n1 + 16*pg;
      fa0 = *(const float4*)ga;       fa1 = *(const float4*)(ga + 4);
      fa2 = *(const float4*)(ga + 8); fa3 = *(const float4*)(ga + 12);
      const float* gb = xb + (size_t)(16*scg) * N_POS + n1 + spp;
      #pragma unroll
      for (int i = 0; i < 16; ++i) v[i] = gb[(size_t)i * N_POS];
    }
    // phase1: S[pos][hd] -> E=exp -> es[hd][pos]
    #pragma unroll
    for (int ip = 0; ip < 2; ++ip){
      const int pt = pth + 4*ip;
      bf16x8 af0 = *(const bf16x8*)&xs_pc[(16*pt + lm)*72 + 8*lg];        // c 0..31
      bf16x8 af1 = *(const bf16x8*)&xs_pc[(16*pt + lm)*72 + 32 + 8*lg];   // c 32..63
      #pragma unroll
      for (int i = 0; i < 4; ++i){
        f32x4 s = (f32x4){0.f,0.f,0.f,0.f};
        s = __builtin_amdgcn_mfma_f32_16x16x32_bf16(af0, wkf[i][0], s, 0,0,0);
        s = __builtin_amdgcn_mfma_f32_16x16x32_bf16(af1, wkf[i][1], s, 0,0,0);
        // lane: pos = 16pt+4lg+r, hd = 16(ht0+i)+lm
        float e0 = __expf(s[0]), e1 = __expf(s[1]);
        float e2 = __expf(s[2]), e3 = __expf(s[3]);
        uint2 pk; pk.x = packbf(e0,e1); pk.y = packbf(e2,e3);
        *(uint2*)&es[(16*(ht0+i) + lm)*136 + 16*pt + 4*lg] = pk;
      }
    }
    __syncthreads();
    // phase2: wave w8 owns hd rows 16w8..16w8+15; K = 128 pos in 4 chunks
    __builtin_amdgcn_s_setprio(1);
    #pragma unroll
    for (int kk = 0; kk < 4; ++kk){
      bf16x8 ea = *(const bf16x8*)&es[(16*w8 + lm)*136 + 32*kk + 8*lg];
      bf16x8 xbf[4];
      #pragma unroll
      for (int n = 0; n < 4; ++n)
        xbf[n] = *(const bf16x8*)&xs_cp[(16*n + lm)*136 + 32*kk + 8*lg];
      #pragma unroll
      for (int n = 0; n < 4; ++n)
        acc[n] = __builtin_amdgcn_mfma_f32_16x16x32_bf16(ea, xbf[n], acc[n], 0,0,0);
      zac = __builtin_amdgcn_mfma_f32_16x16x32_bf16(ea, ones, zac, 0,0,0);
    }
    __builtin_amdgcn_s_setprio(0);
  }

  // epilogue: D-layout row hd = 16w8+4lg+r, col c = 16n+lm
  float* pa = pA + (size_t)blockIdx.x * 8192;
  const int hd0 = 16*w8 + 4*lg;
  #pragma unroll
  for (int n = 0; n < 4; ++n)
    #pragma unroll
    for (int r = 0; r < 4; ++r)
      pa[(size_t)(hd0 + r)*64 + 16*n + lm] = acc[n][r];
  if (lm == 0){
    #pragma unroll
    for (int r = 0; r < 4; ++r)
      pZ[(size_t)blockIdx.x * 128 + hd0 + r] = zac[r];
  }
}

// ---------------------------------------------------------------------------
// kernR1: parallel reduce of partials. grid 64 = 8 batches x 8 slices.
// ---------------------------------------------------------------------------
__global__ __launch_bounds__(256) void kernR1(
    const float* __restrict__ pA, const float* __restrict__ pZ,
    float* __restrict__ Ar, float* __restrict__ Zr, int nch)
{
  const int b = blockIdx.x >> 3, s = blockIdx.x & 7;
  const int off = s * 1024 + threadIdx.x * 4;
  float4 a = make_float4(0.f, 0.f, 0.f, 0.f);
  for (int ch = 0; ch < nch; ++ch){
    float4 v = *(const float4*)&pA[(size_t)(b * nch + ch) * 8192 + off];
    a.x += v.x; a.y += v.y; a.z += v.z; a.w += v.w;
  }
  *(float4*)&Ar[(size_t)b * 8192 + off] = a;
  if (s == 0 && threadIdx.x < 128){
    float z = 0.f;
    for (int ch = 0; ch < nch; ++ch) z += pZ[(size_t)(b * nch + ch) * 128 + threadIdx.x];
    Zr[b * 128 + threadIdx.x] = z;
  }
}

// ---------------------------------------------------------------------------
// kernCM (fused R2+M): per batch:
//   ctx[hd][e] = (A[hd]·Wv[e]) / Z[hd]        (-> LDS cs)
//   T[o][hd] = sum_e w_out[o][32h+e] cs[hd][e]
//   M[o][c]  = sum_hd T[o][hd] Wq[hd][c]
// ---------------------------------------------------------------------------
__global__ __launch_bounds__(256) void kernCM(
    const float* __restrict__ Ar, const float* __restrict__ Zr,
    const float* __restrict__ w_qkv, const float* __restrict__ w_out,
    float* __restrict__ M)
{
  __shared__ float A[128 * 65];
  __shared__ float Z[128];
  __shared__ float cs[128 * 33];
  __shared__ float T[64 * 129];
  const int b = blockIdx.x, t = threadIdx.x;

  #pragma unroll
  for (int k = 0; k < 32; ++k){
    int i = t + 256 * k;
    A[(i >> 6) * 65 + (i & 63)] = Ar[(size_t)b * 8192 + i];
  }
  if (t < 128) Z[t] = Zr[b * 128 + t];
  __syncthreads();

  {
    const int hd = t & 127, h = hd >> 5, e0 = (t >> 7) * 16;
    const float rz = 1.0f / Z[hd];
    for (int je = 0; je < 16; ++je){
      int e = e0 + je;
      const float* wv = w_qkv + (size_t)(256 + 32 * h + e) * 64;   // Wv row
      float a = 0.f;
      #pragma unroll
      for (int c = 0; c < 64; ++c) a = fmaf(A[hd * 65 + c], wv[c], a);
      cs[hd * 33 + e] = a * rz;
    }
  }
  __syncthreads();

  const int o = t & 63, g = t >> 6;
  for (int jh = 0; jh < 32; ++jh){
    int hd = 32 * g + jh;
    const float* wo = w_out + (size_t)o * 128 + 32 * g;
    float a = 0.f;
    #pragma unroll
    for (int e = 0; e < 32; ++e) a = fmaf(wo[e], cs[hd * 33 + e], a);
    T[o * 129 + hd] = a;
  }
  __syncthreads();

  const int c0 = 16 * g;
  float m[16];
  #pragma unroll
  for (int j = 0; j < 16; ++j) m[j] = 0.f;
  for (int hd = 0; hd < 128; ++hd){
    float tv = T[o * 129 + hd];
    const float* wq = w_qkv + (size_t)hd * 64 + c0;
    #pragma unroll
    for (int j = 0; j < 16; ++j) m[j] = fmaf(tv, wq[j], m[j]);
  }
  #pragma unroll
  for (int j = 0; j < 16; ++j) M[(size_t)b * 4096 + o * 64 + c0 + j] = m[j];
}

// ---------------------------------------------------------------------------
// kernO (MFMA): per block: out[64, 256-pos tile] = M_b * x + b_out.
// 4 blocks/CU for latency hiding.
// ---------------------------------------------------------------------------
__global__ __launch_bounds__(256, 4) void kernO(
    const float* __restrict__ x, const float* __restrict__ M,
    const float* __restrict__ b_out, float* __restrict__ out)
{
  __shared__ __align__(16) uint16_t xs[256 * 72];   // [pos][c], 36 KB

  const int t  = threadIdx.x;
  const int wv = t >> 6;
  const int l  = t & 63;
  const int lm = l & 15;
  const int lg = l >> 4;

  const int b  = blockIdx.x / 320;
  const int p0 = (blockIdx.x % 320) * 256;
  const float* xb = x + (size_t)b * 64 * N_POS + p0;

  // B-fragments of M: mb[ot][kk] -> lane holds M[16ot+lm][32kk+8lg+j]
  const float* Mb = M + (size_t)b * 4096;
  bf16x8 mb[4][2];
  float bias[4];
  #pragma unroll
  for (int ot = 0; ot < 4; ++ot){
    bias[ot] = b_out[16*ot + lm];
    #pragma unroll
    for (int kk = 0; kk < 2; ++kk){
      const float* mp = Mb + (size_t)(16*ot + lm)*64 + 32*kk + 8*lg;
      float4 m0 = *(const float4*)mp;
      float4 m1 = *(const float4*)(mp + 4);
      bf16x8 f;
      f[0]=bf16of(m0.x); f[1]=bf16of(m0.y); f[2]=bf16of(m0.z); f[3]=bf16of(m0.w);
      f[4]=bf16of(m1.x); f[5]=bf16of(m1.y); f[6]=bf16of(m1.z); f[7]=bf16of(m1.w);
      mb[ot][kk] = f;
    }
  }

  // stage xs[pos][c]: thread = one pos; per c coalesced across lanes
  #pragma unroll
  for (int cc = 0; cc < 8; ++cc){
    float v[8];
    #pragma unroll
    for (int j = 0; j < 8; ++j)
      v[j] = xb[(size_t)(8*cc + j) * N_POS + t];
    uint4 u;
    u.x = packbf(v[0],v[1]); u.y = packbf(v[2],v[3]);
    u.z = packbf(v[4],v[5]); u.w = packbf(v[6],v[7]);
    *(uint4*)&xs[t*72 + 8*cc] = u;
  }
  __syncthreads();

  float* ob = out + (size_t)b * 64 * N_POS + p0;

  // wave wv: pos-tiles 4wv .. 4wv+3
  #pragma unroll
  for (int ip = 0; ip < 4; ++ip){
    const int pt = 4*wv + ip;
    bf16x8 af0 = *(const bf16x8*)&xs[(16*pt + lm)*72 + 8*lg];        // c 0..31
    bf16x8 af1 = *(const bf16x8*)&xs[(16*pt + lm)*72 + 32 + 8*lg];   // c 32..63
    #pragma unroll
    for (int ot = 0; ot < 4; ++ot){
      f32x4 d = (f32x4){0.f,0.f,0.f,0.f};
      d = __builtin_amdgcn_mfma_f32_16x16x32_bf16(af0, mb[ot][0], d, 0,0,0);
      d = __builtin_amdgcn_mfma_f32_16x16x32_bf16(af1, mb[ot][1], d, 0,0,0);
      // lane: o = 16ot+lm, pos = 16pt + 4lg + r (r=0..3 contiguous)
      float4 st = make_float4(d[0]+bias[ot], d[1]+bias[ot],
                              d[2]+bias[ot], d[3]+bias[ot]);
      *(float4*)&ob[(size_t)(16*ot + lm) * N_POS + 16*pt + 4*lg] = st;
    }
  }
}

// ---------------------------------------------------------------------------
extern "C" void kernel_launch(void* const* d_in, const int* in_sizes, int n_in,
                              void* d_out, int out_size, void* d_ws, size_t ws_size,
                              hipStream_t stream)
{
  const float* x     = (const float*)d_in[0];
  const float* w_qkv = (const float*)d_in[1];
  const float* w_out = (const float*)d_in[2];
  const float* b_out = (const float*)d_in[3];
  float* out = (float*)d_out;
  float* ws  = (float*)d_ws;

  static const int cand[] = {64, 40, 32, 20, 16, 10, 8, 5, 4, 2, 1};
  int nch = 1;
  for (int i = 0; i < 11; ++i){
    size_t need = ((size_t)8 * cand[i] * (8192 + 128)
                   + 8 * 8192 + 8 * 128 + (size_t)8 * 4096) * 4;
    if (need <= ws_size){ nch = cand[i]; break; }
  }
  const int tpc = TILES / nch;

  float* pA  = ws;
  float* pZ  = pA + (size_t)8 * nch * 8192;
  float* Ar  = pZ + (size_t)8 * nch * 128;
  float* Zr  = Ar + (size_t)8 * 8192;
  float* M   = Zr + (size_t)8 * 128;

  kernA<<<8 * nch, 512, 0, stream>>>(x, w_qkv, pA, pZ, nch, tpc);
  kernR1<<<64,     256, 0, stream>>>(pA, pZ, Ar, Zr, nch);
  kernCM<<<8,      256, 0, stream>>>(Ar, Zr, w_qkv, w_out, M);
  kernO<<<2560,    256, 0, stream>>>(x, M, b_out, out);
}